// Round 5
// baseline (2069.131 us; speedup 1.0000x reference)
//
#include <hip/hip_runtime.h>
#include <hip/hip_bf16.h>

typedef _Float16 half8 __attribute__((ext_vector_type(8)));
typedef _Float16 half4 __attribute__((ext_vector_type(4)));
typedef float f32x4 __attribute__((ext_vector_type(4)));

// Geometry: D=256, H=8, A=64, M=400000 (64*6250), N=50000 (16*3125)

__device__ __forceinline__ unsigned short f2bf(float x) {
    unsigned u = __float_as_uint(x);
    u += 0x7fffu + ((u >> 16) & 1u);   // RNE
    return (unsigned short)(u >> 16);
}
__device__ __forceinline__ float bf2f(unsigned short u) {
    return __uint_as_float(((unsigned)u) << 16);
}

// ---------------- weight transpose + f16 convert ----------------
__global__ void k_convert(const float* __restrict__ Wq, const float* __restrict__ Wk,
                          const float* __restrict__ Wv, const float* __restrict__ Wout,
                          _Float16* __restrict__ wqkT, _Float16* __restrict__ wvT,
                          _Float16* __restrict__ woutT)
{
    int gid = blockIdx.x * 256 + threadIdx.x;
    if (gid < 131072) {
        int h = gid >> 14;
        int d = (gid >> 6) & 255;
        int a = gid & 63;
        wqkT[((h * 64 + a) << 8) + d]       = (_Float16)Wq[gid];
        wqkT[(((8 + h) * 64 + a) << 8) + d] = (_Float16)Wk[gid];
        wvT[((h * 64 + a) << 8) + d]        = (_Float16)Wv[gid];
    } else if (gid < 262144) {
        int g = gid - 131072;
        int k = g >> 8, n = g & 255;
        woutT[(n << 9) + k] = (_Float16)Wout[g];
    }
}

// ---------------- counting sort: hist -> 3-stage scan -> scatter ----------------
__global__ void k_hist(const int* __restrict__ index, int* __restrict__ counts, int M) {
    int m = blockIdx.x * 256 + threadIdx.x;
    if (m < M) atomicAdd(&counts[index[m]], 1);
}

__global__ __launch_bounds__(1024) void k_scan1(const int* __restrict__ counts,
                                                int* __restrict__ starts,
                                                int* __restrict__ blocktot, int N) {
    __shared__ int s[1024];
    int b = blockIdx.x, t = threadIdx.x;
    int i = b * 1024 + t;
    int x = (i < N) ? counts[i] : 0;
    s[t] = x;
    __syncthreads();
    #pragma unroll
    for (int off = 1; off < 1024; off <<= 1) {
        int v = (t >= off) ? s[t - off] : 0;
        __syncthreads();
        s[t] += v;
        __syncthreads();
    }
    if (i < N) starts[i] = s[t] - x;
    if (t == 1023) blocktot[b] = s[1023];
}

__global__ void k_scan2(const int* __restrict__ blocktot, int* __restrict__ blockoff, int NC) {
    if (threadIdx.x == 0 && blockIdx.x == 0) {
        int run = 0;
        for (int i = 0; i < NC; ++i) { blockoff[i] = run; run += blocktot[i]; }
    }
}

__global__ __launch_bounds__(1024) void k_scan3(int* __restrict__ starts,
                                                int* __restrict__ cursor,
                                                const int* __restrict__ blockoff,
                                                int N, int M) {
    int b = blockIdx.x, t = threadIdx.x;
    int i = b * 1024 + t;
    if (i < N) {
        int v = starts[i] + blockoff[b];
        starts[i] = v;
        cursor[i] = v;
    }
    if (b == 0 && t == 0) starts[N] = M;
}

__global__ void k_scatteridx(const int* __restrict__ index, int* __restrict__ cursor,
                             int* __restrict__ sorted, int M) {
    int m = blockIdx.x * 256 + threadIdx.x;
    if (m < M) {
        int pos = atomicAdd(&cursor[index[m]], 1);
        sorted[pos] = m;
    }
}

// ---------------- fused q,k,e,v + column-wise sorted reduce ----------------
// Per block: 64 sorted rows. Stage msg->f16 LDS; q/k (n-split-2, low VGPR);
// e=exp(leaky(s)) in-reg; v (n-split-2) scaled by e, packed bf16; transpose
// via LDS v-tile (reusing At space) in two 4-head rounds; each thread reduces
// one column over the 64 sorted rows (wave-uniform seg branches); interior
// segs plain-store, boundary segs atomicAdd. segsum rides as 4 extra columns.
__global__ __launch_bounds__(256, 3) void k_qkve(
    const float* __restrict__ msg, const int* __restrict__ index,
    const int* __restrict__ sorted, const _Float16* __restrict__ wqkT,
    const _Float16* __restrict__ wvT,
    float* __restrict__ segsum, float* __restrict__ acc, int M)
{
    __shared__ char lds[64 * 260 * 2];   // 33280 B: At f16[64][256] swz  /  vt u16[64][260]
    __shared__ int s_id[64];
    __shared__ int s_sg[64];
    const int t = threadIdx.x;

    // bijective XCD-chunked swizzle: consecutive sorted chunks share an XCD L2
    int nwg = gridDim.x;
    int qc = nwg >> 3, rc = nwg & 7;
    int xcd = blockIdx.x & 7, ofs = blockIdx.x >> 3;
    int b = ((xcd < rc) ? xcd * (qc + 1) : rc * (qc + 1) + (xcd - rc) * qc) + ofs;
    const long m0 = (long)b * 64;

    if (t < 64) {
        int sid = sorted[m0 + t];
        s_id[t] = sid;
        s_sg[t] = index[sid];
    }
    __syncthreads();

    // stage gathered 64x256 f32 -> f16 LDS (XOR-swizzled rows)
    const float4* msgf4 = (const float4*)msg;
    #pragma unroll
    for (int it = 0; it < 16; ++it) {
        int e4 = it * 256 + t;
        int row = e4 >> 6, c4 = e4 & 63;
        float4 v = msgf4[(long)s_id[row] * 64 + c4];
        half4 hv = {(_Float16)v.x, (_Float16)v.y, (_Float16)v.z, (_Float16)v.w};
        int bb = (row << 9) + (c4 << 3);
        bb ^= (row & 7) << 4;
        *(half4*)(lds + bb) = hv;
    }
    __syncthreads();

    const int w = t >> 6, l = t & 63, lr = l & 15, lk = l >> 4;
    const int gl0 = s_sg[0], ghi = s_sg[63];
    const f32x4 zero = {0.f, 0.f, 0.f, 0.f};

    float ev[2][4][4];      // e per [head-in-pair][r][j]
    unsigned pk[2][32];     // packed bf16 e*v per [head][nh*16+n2*8+r*2+jp]

    // ---- q,k scores for both heads (n-split-2 keeps VGPR low) ----
    #pragma unroll
    for (int hi = 0; hi < 2; ++hi) {
        const int h = w * 2 + hi;
        f32x4 p[4] = {zero, zero, zero, zero};
        #pragma unroll
        for (int nh = 0; nh < 2; ++nh) {
            f32x4 aq[2][4], ak[2][4];
            #pragma unroll
            for (int n2 = 0; n2 < 2; ++n2)
                #pragma unroll
                for (int r = 0; r < 4; ++r) { aq[n2][r] = zero; ak[n2][r] = zero; }
            #pragma unroll
            for (int k0 = 0; k0 < 8; ++k0) {
                half8 a[4];
                #pragma unroll
                for (int r = 0; r < 4; ++r) {
                    int row = r * 16 + lr;
                    int bb = (row << 9) + ((k0 * 32 + lk * 8) << 1);
                    bb ^= (row & 7) << 4;
                    a[r] = *(const half8*)(lds + bb);
                }
                #pragma unroll
                for (int n2 = 0; n2 < 2; ++n2) {
                    int n = nh * 2 + n2;
                    half8 bq = *(const half8*)(wqkT + ((h * 64 + n * 16 + lr) << 8) + k0 * 32 + lk * 8);
                    half8 bk = *(const half8*)(wqkT + (((8 + h) * 64 + n * 16 + lr) << 8) + k0 * 32 + lk * 8);
                    #pragma unroll
                    for (int r = 0; r < 4; ++r) {
                        aq[n2][r] = __builtin_amdgcn_mfma_f32_16x16x32_f16(a[r], bq, aq[n2][r], 0, 0, 0);
                        ak[n2][r] = __builtin_amdgcn_mfma_f32_16x16x32_f16(a[r], bk, ak[n2][r], 0, 0, 0);
                    }
                }
            }
            #pragma unroll
            for (int n2 = 0; n2 < 2; ++n2)
                #pragma unroll
                for (int r = 0; r < 4; ++r)
                    p[r] += aq[n2][r] * ak[n2][r];
        }
        // butterfly over the 16-lane col group; all lanes end with full sums
        #pragma unroll
        for (int off = 1; off < 16; off <<= 1) {
            #pragma unroll
            for (int r = 0; r < 4; ++r) {
                p[r][0] += __shfl_xor(p[r][0], off);
                p[r][1] += __shfl_xor(p[r][1], off);
                p[r][2] += __shfl_xor(p[r][2], off);
                p[r][3] += __shfl_xor(p[r][3], off);
            }
        }
        #pragma unroll
        for (int r = 0; r < 4; ++r) {
            #pragma unroll
            for (int j = 0; j < 4; ++j) {
                float s = p[r][j];
                s = (s >= 0.f) ? s : 0.2f * s;
                ev[hi][r][j] = __expf(s);   // no shift: |s|<~45 << 88, f32-safe
            }
        }
    }

    // ---- v projection, e-scale, pack bf16 (n-split-2) ----
    #pragma unroll
    for (int hi = 0; hi < 2; ++hi) {
        const int h = w * 2 + hi;
        #pragma unroll
        for (int nh = 0; nh < 2; ++nh) {
            f32x4 av[2][4];
            #pragma unroll
            for (int n2 = 0; n2 < 2; ++n2)
                #pragma unroll
                for (int r = 0; r < 4; ++r) av[n2][r] = zero;
            #pragma unroll
            for (int k0 = 0; k0 < 8; ++k0) {
                half8 a[4];
                #pragma unroll
                for (int r = 0; r < 4; ++r) {
                    int row = r * 16 + lr;
                    int bb = (row << 9) + ((k0 * 32 + lk * 8) << 1);
                    bb ^= (row & 7) << 4;
                    a[r] = *(const half8*)(lds + bb);
                }
                #pragma unroll
                for (int n2 = 0; n2 < 2; ++n2) {
                    int n = nh * 2 + n2;
                    half8 bv = *(const half8*)(wvT + ((h * 64 + n * 16 + lr) << 8) + k0 * 32 + lk * 8);
                    #pragma unroll
                    for (int r = 0; r < 4; ++r)
                        av[n2][r] = __builtin_amdgcn_mfma_f32_16x16x32_f16(a[r], bv, av[n2][r], 0, 0, 0);
                }
            }
            #pragma unroll
            for (int n2 = 0; n2 < 2; ++n2) {
                #pragma unroll
                for (int r = 0; r < 4; ++r) {
                    #pragma unroll
                    for (int jp = 0; jp < 2; ++jp) {
                        float x0 = av[n2][r][2 * jp]     * ev[hi][r][2 * jp];
                        float x1 = av[n2][r][2 * jp + 1] * ev[hi][r][2 * jp + 1];
                        pk[hi][nh * 16 + n2 * 8 + r * 2 + jp] =
                            (unsigned)f2bf(x0) | ((unsigned)f2bf(x1) << 16);
                    }
                }
            }
        }
    }

    __syncthreads();   // At dead; reuse LDS as v-tile [64][260] u16 (bf16)
    unsigned short* vt = (unsigned short*)lds;

    #pragma unroll
    for (int ra = 0; ra < 2; ++ra) {
        // waves (w>>1)==ra write heads ra*4..ra*4+3 into tile cols 0..255,
        // plus their e-values into cols 256..259
        if ((w >> 1) == ra) {
            int wl = w & 1;
            #pragma unroll
            for (int hi = 0; hi < 2; ++hi) {
                int colh = (wl * 2 + hi) * 64;
                #pragma unroll
                for (int nh = 0; nh < 2; ++nh)
                    #pragma unroll
                    for (int n2 = 0; n2 < 2; ++n2)
                        #pragma unroll
                        for (int r = 0; r < 4; ++r)
                            #pragma unroll
                            for (int jp = 0; jp < 2; ++jp) {
                                unsigned v = pk[hi][nh * 16 + n2 * 8 + r * 2 + jp];
                                int c = colh + (nh * 2 + n2) * 16 + lr;
                                int row0 = r * 16 + lk * 4 + 2 * jp;
                                vt[row0 * 260 + c] = (unsigned short)v;
                                vt[(row0 + 1) * 260 + c] = (unsigned short)(v >> 16);
                            }
                if (lr == 0) {
                    #pragma unroll
                    for (int r = 0; r < 4; ++r)
                        #pragma unroll
                        for (int j = 0; j < 4; ++j)
                            vt[(r * 16 + lk * 4 + j) * 260 + 256 + wl * 2 + hi] =
                                f2bf(ev[hi][r][j]);
                }
            }
        }
        __syncthreads();

        // column-wise sorted reduce: thread t owns tile col t (global ra*256+t);
        // seg-change branches are wave-uniform (s_sg same across lanes)
        {
            int col = ra * 256 + t;
            int cur = s_sg[0];
            float a = bf2f(vt[t]);
            #pragma unroll
            for (int row = 1; row < 64; ++row) {
                float x = bf2f(vt[row * 260 + t]);
                int g = s_sg[row];
                if (g == cur) a += x;
                else {
                    float* dst = acc + (long)cur * 512 + col;
                    if (cur == gl0 || cur == ghi) atomicAdd(dst, a); else *dst = a;
                    cur = g; a = x;
                }
            }
            float* dst = acc + (long)cur * 512 + col;
            if (cur == gl0 || cur == ghi) atomicAdd(dst, a); else *dst = a;
        }
        // e-columns -> segsum (heads ra*4 .. ra*4+3)
        if (t < 4) {
            int hd = ra * 4 + t;
            int cur = s_sg[0];
            float a = bf2f(vt[256 + t]);
            for (int row = 1; row < 64; ++row) {
                float x = bf2f(vt[row * 260 + 256 + t]);
                int g = s_sg[row];
                if (g == cur) a += x;
                else {
                    float* dst = segsum + (long)cur * 8 + hd;
                    if (cur == gl0 || cur == ghi) atomicAdd(dst, a); else *dst = a;
                    cur = g; a = x;
                }
            }
            float* dst = segsum + (long)cur * 8 + hd;
            if (cur == gl0 || cur == ghi) atomicAdd(dst, a); else *dst = a;
        }
        __syncthreads();
    }
}

// ---------------- out = (acc/segsum) @ Wout + bout ----------------
__global__ __launch_bounds__(256) void k_out(
    const float* __restrict__ acc, const float* __restrict__ segsum,
    const _Float16* __restrict__ woutT, const float* __restrict__ bout,
    float* __restrict__ out, int N)
{
    __shared__ _Float16 At[64 * 512];  // 64 KB
    char* lds = (char*)At;
    const int t = threadIdx.x;
    const long n0 = (long)blockIdx.x * 64;

    #pragma unroll
    for (int it = 0; it < 32; ++it) {
        int e4 = it * 256 + t;
        int row = e4 >> 7;
        int c4 = (e4 & 127) << 2;
        long gr = n0 + row;
        float4 v = {0.f, 0.f, 0.f, 0.f};
        float inv = 0.f;
        if (gr < N) {
            v = ((const float4*)acc)[gr * 128 + (e4 & 127)];
            float ss = segsum[gr * 8 + (c4 >> 6)];
            inv = (ss > 0.f) ? 1.f / ss : 0.f;
        }
        half4 hv = {(_Float16)(v.x * inv), (_Float16)(v.y * inv),
                    (_Float16)(v.z * inv), (_Float16)(v.w * inv)};
        int b = (row << 10) + (c4 << 1);
        b ^= (row & 7) << 4;
        *(half4*)(lds + b) = hv;
    }
    __syncthreads();

    const int w = t >> 6, l = t & 63, lr = l & 15, lk = l >> 4;
    const f32x4 zero = {0.f, 0.f, 0.f, 0.f};
    f32x4 ac[4][4];
    #pragma unroll
    for (int r = 0; r < 4; ++r)
        #pragma unroll
        for (int n = 0; n < 4; ++n) ac[r][n] = zero;
    #pragma unroll
    for (int k0 = 0; k0 < 16; ++k0) {
        half8 a[4];
        #pragma unroll
        for (int r = 0; r < 4; ++r) {
            int row = r * 16 + lr;
            int b = (row << 10) + ((k0 * 32 + lk * 8) << 1);
            b ^= (row & 7) << 4;
            a[r] = *(const half8*)(lds + b);
        }
        #pragma unroll
        for (int n = 0; n < 4; ++n) {
            half8 bw = *(const half8*)(woutT + ((w * 64 + n * 16 + lr) << 9) + k0 * 32 + lk * 8);
            #pragma unroll
            for (int r = 0; r < 4; ++r)
                ac[r][n] = __builtin_amdgcn_mfma_f32_16x16x32_f16(a[r], bw, ac[r][n], 0, 0, 0);
        }
    }
    #pragma unroll
    for (int n = 0; n < 4; ++n) {
        int col = w * 64 + n * 16 + lr;
        float bb = bout[col];
        #pragma unroll
        for (int r = 0; r < 4; ++r) {
            #pragma unroll
            for (int j = 0; j < 4; ++j) {
                long row = n0 + r * 16 + lk * 4 + j;
                if (row < N) out[row * 256 + col] = ac[r][n][j] + bb;
            }
        }
    }
}

extern "C" void kernel_launch(void* const* d_in, const int* in_sizes, int n_in,
                              void* d_out, int out_size, void* d_ws, size_t ws_size,
                              hipStream_t stream)
{
    const float* msg   = (const float*)d_in[0];
    const int*   index = (const int*)d_in[1];
    const float* Wq    = (const float*)d_in[4];
    const float* Wk    = (const float*)d_in[5];
    const float* Wv    = (const float*)d_in[6];
    const float* Wout  = (const float*)d_in[7];
    const float* bout  = (const float*)d_in[8];
    float* out = (float*)d_out;

    const int M = in_sizes[0] / 256;   // 400000
    const int N = out_size / 256;      // 50000
    const int NC = (N + 1023) / 1024;  // 49 scan chunks

    char* ws = (char*)d_ws;
    _Float16* wqkT  = (_Float16*)(ws);              // 524288 B
    _Float16* wvT   = (_Float16*)(ws + 524288);     // 262144 B
    _Float16* woutT = (_Float16*)(ws + 786432);     // 262144 B
    size_t o = 1048576;
    float* segsum = (float*)(ws + o);                                   // N*32 B
    float* acc    = (float*)(ws + o + (size_t)N * 32);                  // N*2048 B
    char*  p2     = ws + o + (size_t)N * 32 + (size_t)N * 2048;
    int* counts   = (int*)(p2);                     // N*4
    int* cursor   = (int*)(p2 + (size_t)N * 4);     // N*4
    int* starts   = (int*)(p2 + (size_t)N * 8);     // (N+1)*4
    int* sorted   = (int*)(p2 + (size_t)N * 12 + 4);// M*4
    int* blocktot = (int*)(p2 + (size_t)N * 12 + 4 + (size_t)M * 4);
    int* blockoff = blocktot + NC;

    // zero segsum + acc (boundary atomics / empty segs) + counts
    hipMemsetAsync(ws + o, 0, (size_t)N * 32 + (size_t)N * 2048 + (size_t)N * 4, stream);

    k_convert<<<1024, 256, 0, stream>>>(Wq, Wk, Wv, Wout, wqkT, wvT, woutT);
    k_hist<<<(M + 255) / 256, 256, 0, stream>>>(index, counts, M);
    k_scan1<<<NC, 1024, 0, stream>>>(counts, starts, blocktot, N);
    k_scan2<<<1, 64, 0, stream>>>(blocktot, blockoff, NC);
    k_scan3<<<NC, 1024, 0, stream>>>(starts, cursor, blockoff, N, M);
    k_scatteridx<<<(M + 255) / 256, 256, 0, stream>>>(index, cursor, sorted, M);
    k_qkve<<<M / 64, 256, 0, stream>>>(msg, index, sorted, wqkT, wvT, segsum, acc, M);
    k_out<<<(N + 63) / 64, 256, 0, stream>>>(acc, segsum, woutT, bout, out, N);
}

// Round 6
// 1053.892 us; speedup vs baseline: 1.9633x; 1.9633x over previous
//
#include <hip/hip_runtime.h>
#include <hip/hip_bf16.h>

typedef _Float16 half8 __attribute__((ext_vector_type(8)));
typedef _Float16 half4 __attribute__((ext_vector_type(4)));
typedef float f32x4 __attribute__((ext_vector_type(4)));

// Geometry: D=256, H=8, A=64, M=400000 (128*3125), N=50000

__device__ __forceinline__ unsigned short f2bf(float x) {
    unsigned u = __float_as_uint(x);
    u += 0x7fffu + ((u >> 16) & 1u);   // RNE
    return (unsigned short)(u >> 16);
}
__device__ __forceinline__ float bf2f(unsigned x16) {
    return __uint_as_float(x16 << 16);
}

// ---------------- weight transpose + f16 convert (PRE-SWIZZLED rows) ----------------
// wqkT/wvT rows are the output-cols (64 per head); within-row f16 index is
// XOR-swizzled: d' = d ^ ((row&7)<<3)  (byte ^ (row&7)<<4) so a LINEAR
// global_load_lds copy yields the swizzled LDS layout the readers expect.
__global__ void k_convert(const float* __restrict__ Wq, const float* __restrict__ Wk,
                          const float* __restrict__ Wv, const float* __restrict__ Wout,
                          _Float16* __restrict__ wqkT, _Float16* __restrict__ wvT,
                          _Float16* __restrict__ woutT)
{
    int gid = blockIdx.x * 256 + threadIdx.x;
    if (gid < 131072) {
        int h = gid >> 14;
        int d = (gid >> 6) & 255;
        int a = gid & 63;
        int dq = d ^ ((a & 7) << 3);
        wqkT[((h * 64 + a) << 8) + dq]       = (_Float16)Wq[gid];
        wqkT[(((8 + h) * 64 + a) << 8) + dq] = (_Float16)Wk[gid];
        wvT[((h * 64 + a) << 8) + dq]        = (_Float16)Wv[gid];
    } else if (gid < 262144) {
        int g = gid - 131072;
        int k = g >> 8, n = g & 255;
        woutT[(n << 9) + k] = (_Float16)Wout[g];   // k_out path: unswizzled
    }
}

// ---------------- counting sort: hist -> 3-stage scan -> scatter ----------------
__global__ void k_hist(const int* __restrict__ index, int* __restrict__ counts, int M) {
    int m = blockIdx.x * 256 + threadIdx.x;
    if (m < M) atomicAdd(&counts[index[m]], 1);
}

__global__ __launch_bounds__(1024) void k_scan1(const int* __restrict__ counts,
                                                int* __restrict__ starts,
                                                int* __restrict__ blocktot, int N) {
    __shared__ int s[1024];
    int b = blockIdx.x, t = threadIdx.x;
    int i = b * 1024 + t;
    int x = (i < N) ? counts[i] : 0;
    s[t] = x;
    __syncthreads();
    #pragma unroll
    for (int off = 1; off < 1024; off <<= 1) {
        int v = (t >= off) ? s[t - off] : 0;
        __syncthreads();
        s[t] += v;
        __syncthreads();
    }
    if (i < N) starts[i] = s[t] - x;
    if (t == 1023) blocktot[b] = s[1023];
}

__global__ void k_scan2(const int* __restrict__ blocktot, int* __restrict__ blockoff, int NC) {
    if (threadIdx.x == 0 && blockIdx.x == 0) {
        int run = 0;
        for (int i = 0; i < NC; ++i) { blockoff[i] = run; run += blocktot[i]; }
    }
}

__global__ __launch_bounds__(1024) void k_scan3(int* __restrict__ starts,
                                                int* __restrict__ cursor,
                                                const int* __restrict__ blockoff,
                                                int N, int M) {
    int b = blockIdx.x, t = threadIdx.x;
    int i = b * 1024 + t;
    if (i < N) {
        int v = starts[i] + blockoff[b];
        starts[i] = v;
        cursor[i] = v;
    }
    if (b == 0 && t == 0) starts[N] = M;
}

__global__ void k_scatteridx(const int* __restrict__ index, int* __restrict__ cursor,
                             int* __restrict__ sorted, int* __restrict__ segsorted, int M) {
    int m = blockIdx.x * 256 + threadIdx.x;
    if (m < M) {
        int idx = index[m];
        int pos = atomicAdd(&cursor[idx], 1);
        sorted[pos] = m;
        segsorted[pos] = idx;
    }
}

// ---------------- proj GEMM: 128 sorted rows x (q,k,v for 8 heads) ----------------
__device__ __forceinline__ void stage_panel(const _Float16* __restrict__ src,
                                            char* ldsbase, int w, int lane)
{
    const char* g = (const char*)src;
    #pragma unroll
    for (int i = 0; i < 4; ++i) {
        int off = (i * 8 + w) * 1024;
        __builtin_amdgcn_global_load_lds(
            (const __attribute__((address_space(1))) unsigned int*)(g + off + lane * 16),
            (__attribute__((address_space(3))) unsigned int*)(ldsbase + off),
            16, 0, 0);
    }
}

__device__ __forceinline__ void panel_mm(const char* __restrict__ Ah,
                                         const char* __restrict__ Bb,
                                         int w, int lr, int lk, f32x4 acc[4])
{
    const f32x4 zero = {0.f, 0.f, 0.f, 0.f};
    #pragma unroll
    for (int n = 0; n < 4; ++n) acc[n] = zero;
    #pragma unroll
    for (int k0 = 0; k0 < 8; ++k0) {
        int arow = w * 16 + lr;
        int ab = (arow << 9) + ((k0 * 32 + lk * 8) << 1);
        ab ^= (arow & 7) << 4;
        half8 a = *(const half8*)(Ah + ab);
        #pragma unroll
        for (int n = 0; n < 4; ++n) {
            int brow = n * 16 + lr;
            int bb = (brow << 9) + ((k0 * 32 + lk * 8) << 1);
            bb ^= (brow & 7) << 4;
            half8 bf = *(const half8*)(Bb + bb);
            acc[n] = __builtin_amdgcn_mfma_f32_16x16x32_f16(a, bf, acc[n], 0, 0, 0);
        }
    }
}

__global__ __launch_bounds__(512) void k_proj(
    const float* __restrict__ msg, const int* __restrict__ sorted,
    const _Float16* __restrict__ wqkT, const _Float16* __restrict__ wvT,
    unsigned short* __restrict__ evbuf, float* __restrict__ e_glb, long mb0)
{
    __shared__ _Float16 Ah[128 * 256];     // 64 KB, swizzled
    __shared__ _Float16 Bl[2][64 * 256];   // 2 x 32 KB, swizzled (via pre-swz source)
    char* Ahc = (char*)Ah;
    const int t = threadIdx.x;
    const int w = t >> 6, l = t & 63, lr = l & 15, lk = l >> 4;
    const long m0 = mb0 + (long)blockIdx.x * 128;

    // stage A: wave w stages rows it*8+w (one full msg row per iteration)
    const float4* msgf4 = (const float4*)msg;
    #pragma unroll
    for (int it = 0; it < 16; ++it) {
        int row = it * 8 + w;
        int sid = sorted[m0 + row];                  // wave-uniform scalar load
        float4 v = msgf4[(long)sid * 64 + l];
        half4 hv = {(_Float16)v.x, (_Float16)v.y, (_Float16)v.z, (_Float16)v.w};
        int b = (row << 9) + (l << 3);
        b ^= (row & 7) << 4;
        *(half4*)(Ahc + b) = hv;
    }
    stage_panel(wqkT, (char*)Bl[0], w, l);           // q panel, head 0
    __syncthreads();

    int buf = 0;
    f32x4 aq[4];
    #pragma unroll 1
    for (int h = 0; h < 8; ++h) {
        // ---- Q compute; stage K ----
        stage_panel(wqkT + ((8 + h) * 64) * 256, (char*)Bl[buf ^ 1], w, l);
        panel_mm(Ahc, (const char*)Bl[buf], w, lr, lk, aq);
        __syncthreads(); buf ^= 1;

        // ---- K compute; stage V; finish score -> e ----
        stage_panel(wvT + (h * 64) * 256, (char*)Bl[buf ^ 1], w, l);
        f32x4 ak[4];
        panel_mm(Ahc, (const char*)Bl[buf], w, lr, lk, ak);
        f32x4 p = aq[0] * ak[0] + aq[1] * ak[1] + aq[2] * ak[2] + aq[3] * ak[3];
        #pragma unroll
        for (int off = 1; off < 16; off <<= 1) {
            p[0] += __shfl_xor(p[0], off);
            p[1] += __shfl_xor(p[1], off);
            p[2] += __shfl_xor(p[2], off);
            p[3] += __shfl_xor(p[3], off);
        }
        f32x4 ev;
        #pragma unroll
        for (int j = 0; j < 4; ++j) {
            float s = p[j];
            s = (s >= 0.f) ? s : 0.2f * s;
            ev[j] = __expf(s);      // |s| <~ 45 << 88: f32-safe unnormalized
        }
        if (lr == 0) {
            #pragma unroll
            for (int j = 0; j < 4; ++j)
                e_glb[(m0 + w * 16 + lk * 4 + j) * 8 + h] = ev[j];
        }
        __syncthreads(); buf ^= 1;

        // ---- V compute; stage next Q; store e*v bf16 by sorted position ----
        if (h < 7) stage_panel(wqkT + ((h + 1) * 64) * 256, (char*)Bl[buf ^ 1], w, l);
        f32x4 av[4];
        panel_mm(Ahc, (const char*)Bl[buf], w, lr, lk, av);
        long rbase = m0 - mb0 + w * 16 + lk * 4;
        #pragma unroll
        for (int n = 0; n < 4; ++n) {
            int col = h * 64 + n * 16 + lr;
            #pragma unroll
            for (int j = 0; j < 4; ++j)
                evbuf[(rbase + j) * 512 + col] = f2bf(av[n][j] * ev[j]);
        }
        __syncthreads(); buf ^= 1;
    }
}

// ---------------- reduce: contiguous sorted stream, run-combined ----------------
__global__ __launch_bounds__(256) void k_reduce(
    const unsigned* __restrict__ evbuf, const float* __restrict__ e_glb,
    const int* __restrict__ segsorted, float* __restrict__ segsum,
    float* __restrict__ acc, long mb0)
{
    __shared__ int s_sg[64];
    const int t = threadIdx.x;
    const long r0 = mb0 + (long)blockIdx.x * 64;
    if (t < 64) s_sg[t] = segsorted[r0 + t];
    __syncthreads();
    const int gl0 = s_sg[0], ghi = s_sg[63];

    const unsigned* src = evbuf + (r0 - mb0) * 256 + t;   // row stride 256 u32
    unsigned va[8], vb[8];
    #pragma unroll
    for (int i = 0; i < 8; ++i) va[i] = src[i * 256];

    float a0 = 0.f, a1 = 0.f;
    int cur = gl0;
    #pragma unroll
    for (int g = 0; g < 8; ++g) {
        if ((g & 1) == 0) {
            if (g < 7) {
                #pragma unroll
                for (int i = 0; i < 8; ++i) vb[i] = src[((g + 1) * 8 + i) * 256];
            }
            #pragma unroll
            for (int i = 0; i < 8; ++i) {
                unsigned x = va[i];
                float lo = bf2f(x & 0xffffu), hi = bf2f(x >> 16);
                int sg = s_sg[g * 8 + i];
                if (sg != cur) {
                    float* d = acc + (long)cur * 512 + t * 2;
                    if (cur == gl0 || cur == ghi) { atomicAdd(d, a0); atomicAdd(d + 1, a1); }
                    else *(float2*)d = make_float2(a0, a1);
                    cur = sg; a0 = lo; a1 = hi;
                } else { a0 += lo; a1 += hi; }
            }
        } else {
            if (g < 7) {
                #pragma unroll
                for (int i = 0; i < 8; ++i) va[i] = src[((g + 1) * 8 + i) * 256];
            }
            #pragma unroll
            for (int i = 0; i < 8; ++i) {
                unsigned x = vb[i];
                float lo = bf2f(x & 0xffffu), hi = bf2f(x >> 16);
                int sg = s_sg[g * 8 + i];
                if (sg != cur) {
                    float* d = acc + (long)cur * 512 + t * 2;
                    if (cur == gl0 || cur == ghi) { atomicAdd(d, a0); atomicAdd(d + 1, a1); }
                    else *(float2*)d = make_float2(a0, a1);
                    cur = sg; a0 = lo; a1 = hi;
                } else { a0 += lo; a1 += hi; }
            }
        }
    }
    {
        float* d = acc + (long)cur * 512 + t * 2;
        if (cur == gl0 || cur == ghi) { atomicAdd(d, a0); atomicAdd(d + 1, a1); }
        else *(float2*)d = make_float2(a0, a1);
    }

    // segsum: 8 threads walk the e-file (f32, sorted order)
    if (t < 8) {
        float s = 0.f;
        int cur2 = gl0;
        #pragma unroll 8
        for (int row = 0; row < 64; ++row) {
            float x = e_glb[(r0 + row) * 8 + t];
            int sg = s_sg[row];
            if (sg != cur2) {
                float* d = segsum + (long)cur2 * 8 + t;
                if (cur2 == gl0 || cur2 == ghi) atomicAdd(d, s); else *d = s;
                cur2 = sg; s = x;
            } else s += x;
        }
        float* d = segsum + (long)cur2 * 8 + t;
        if (cur2 == gl0 || cur2 == ghi) atomicAdd(d, s); else *d = s;
    }
}

// ---------------- out = (acc/segsum) @ Wout + bout ----------------
__global__ __launch_bounds__(256) void k_out(
    const float* __restrict__ acc, const float* __restrict__ segsum,
    const _Float16* __restrict__ woutT, const float* __restrict__ bout,
    float* __restrict__ out, int N)
{
    __shared__ _Float16 At[64 * 512];  // 64 KB
    char* lds = (char*)At;
    const int t = threadIdx.x;
    const long n0 = (long)blockIdx.x * 64;

    #pragma unroll
    for (int it = 0; it < 32; ++it) {
        int e4 = it * 256 + t;
        int row = e4 >> 7;
        int c4 = (e4 & 127) << 2;
        long gr = n0 + row;
        float4 v = {0.f, 0.f, 0.f, 0.f};
        float inv = 0.f;
        if (gr < N) {
            v = ((const float4*)acc)[gr * 128 + (e4 & 127)];
            float ss = segsum[gr * 8 + (c4 >> 6)];
            inv = (ss > 0.f) ? 1.f / ss : 0.f;
        }
        half4 hv = {(_Float16)(v.x * inv), (_Float16)(v.y * inv),
                    (_Float16)(v.z * inv), (_Float16)(v.w * inv)};
        int b = (row << 10) + (c4 << 1);
        b ^= (row & 7) << 4;
        *(half4*)(lds + b) = hv;
    }
    __syncthreads();

    const int w = t >> 6, l = t & 63, lr = l & 15, lk = l >> 4;
    const f32x4 zero = {0.f, 0.f, 0.f, 0.f};
    f32x4 ac[4][4];
    #pragma unroll
    for (int r = 0; r < 4; ++r)
        #pragma unroll
        for (int n = 0; n < 4; ++n) ac[r][n] = zero;
    #pragma unroll
    for (int k0 = 0; k0 < 16; ++k0) {
        half8 a[4];
        #pragma unroll
        for (int r = 0; r < 4; ++r) {
            int row = r * 16 + lr;
            int b = (row << 10) + ((k0 * 32 + lk * 8) << 1);
            b ^= (row & 7) << 4;
            a[r] = *(const half8*)(lds + b);
        }
        #pragma unroll
        for (int n = 0; n < 4; ++n) {
            half8 bw = *(const half8*)(woutT + ((w * 64 + n * 16 + lr) << 9) + k0 * 32 + lk * 8);
            #pragma unroll
            for (int r = 0; r < 4; ++r)
                ac[r][n] = __builtin_amdgcn_mfma_f32_16x16x32_f16(a[r], bw, ac[r][n], 0, 0, 0);
        }
    }
    #pragma unroll
    for (int n = 0; n < 4; ++n) {
        int col = w * 64 + n * 16 + lr;
        float bb = bout[col];
        #pragma unroll
        for (int r = 0; r < 4; ++r) {
            #pragma unroll
            for (int j = 0; j < 4; ++j) {
                long row = n0 + r * 16 + lk * 4 + j;
                if (row < N) out[row * 256 + col] = ac[r][n][j] + bb;
            }
        }
    }
}

extern "C" void kernel_launch(void* const* d_in, const int* in_sizes, int n_in,
                              void* d_out, int out_size, void* d_ws, size_t ws_size,
                              hipStream_t stream)
{
    const float* msg   = (const float*)d_in[0];
    const int*   index = (const int*)d_in[1];
    const float* Wq    = (const float*)d_in[4];
    const float* Wk    = (const float*)d_in[5];
    const float* Wv    = (const float*)d_in[6];
    const float* Wout  = (const float*)d_in[7];
    const float* bout  = (const float*)d_in[8];
    float* out = (float*)d_out;

    const int M = in_sizes[0] / 256;   // 400000
    const int N = out_size / 256;      // 50000
    const int NC = (N + 1023) / 1024;  // 49 scan chunks

    char* ws = (char*)d_ws;
    _Float16* wqkT  = (_Float16*)(ws);              // 524288 B
    _Float16* wvT   = (_Float16*)(ws + 524288);     // 262144 B
    _Float16* woutT = (_Float16*)(ws + 786432);     // 262144 B
    size_t o = 1048576;
    float* segsum   = (float*)(ws + o);                       // N*32
    float* acc      = (float*)(ws + o + (size_t)N * 32);      // N*2048
    char*  p2       = ws + o + (size_t)N * 2080;
    int* counts     = (int*)(p2);                             // N*4
    int* cursor     = (int*)(p2 + (size_t)N * 4);             // N*4
    int* starts     = (int*)(p2 + (size_t)N * 8);             // (N+1)*4
    char* p3        = p2 + (((size_t)N * 12 + 4 + 63) & ~(size_t)63);
    int* sorted     = (int*)(p3);                             // M*4
    int* segsorted  = (int*)(p3 + (size_t)M * 4);             // M*4
    int* blocktot   = (int*)(p3 + (size_t)M * 8);             // 256 B
    int* blockoff   = (int*)(p3 + (size_t)M * 8 + 256);       // 256 B
    float* e_glb    = (float*)(p3 + (size_t)M * 8 + 512);     // M*32
    size_t evoff    = (size_t)(p3 - ws) + (size_t)M * 8 + 512 + (size_t)M * 32;
    evoff = (evoff + 1023) & ~(size_t)1023;
    unsigned short* evbuf = (unsigned short*)(ws + evoff);

    // chunk rows: bounded by remaining workspace, cap 102400, multiple of 128
    long CH = 102400;
    if (ws_size > evoff) {
        long fit = (long)((ws_size - evoff) / 1024);   // 1024 B per row
        if (fit < CH) CH = fit;
    }
    CH -= CH % 128;
    if (CH < 128) CH = 128;

    // zero segsum + acc + counts (contiguous)
    hipMemsetAsync(ws + o, 0, (size_t)N * 2080 + (size_t)N * 4, stream);

    k_convert<<<1024, 256, 0, stream>>>(Wq, Wk, Wv, Wout, wqkT, wvT, woutT);
    k_hist<<<(M + 255) / 256, 256, 0, stream>>>(index, counts, M);
    k_scan1<<<NC, 1024, 0, stream>>>(counts, starts, blocktot, N);
    k_scan2<<<1, 64, 0, stream>>>(blocktot, blockoff, NC);
    k_scan3<<<NC, 1024, 0, stream>>>(starts, cursor, blockoff, N, M);
    k_scatteridx<<<(M + 255) / 256, 256, 0, stream>>>(index, cursor, sorted, segsorted, M);

    long base = 0;
    while (base < M) {
        long rows = M - base;
        if (rows > CH) rows = CH;
        k_proj<<<(int)(rows / 128), 512, 0, stream>>>(msg, sorted, wqkT, wvT,
                                                      evbuf, e_glb, base);
        k_reduce<<<(int)(rows / 64), 256, 0, stream>>>((const unsigned*)evbuf, e_glb,
                                                       segsorted, segsum, acc, base);
        base += rows;
    }
    k_out<<<(N + 63) / 64, 256, 0, stream>>>(acc, segsum, woutT, bout, out, N);
}